// Round 4
// baseline (305.319 us; speedup 1.0000x reference)
//
#include <hip/hip_runtime.h>

// CausalSALayer: post-norm transformer decoder layer on gfx950.
// B=2, N=2048, D=1024, H=16, dk=64, FFN=4096. bf16 MFMA compute, f32 accum.

#define DEV __device__ __forceinline__

typedef __attribute__((ext_vector_type(4)))  float f32x4;
typedef __attribute__((ext_vector_type(16))) float f32x16;
typedef __attribute__((ext_vector_type(8)))  short s16x8;

static constexpr int Bb   = 2;
static constexpr int NN   = 2048;
static constexpr int DM   = 1024;
static constexpr int HH   = 16;
static constexpr int DK   = 64;
static constexpr int FF   = 4096;
static constexpr int ROWS = Bb * NN;  // 4096

#define AS1(p) ((const __attribute__((address_space(1))) void*)(p))
#define AS3(p) ((__attribute__((address_space(3))) void*)(p))

DEV unsigned short f2bf(float f) {
  unsigned u = __float_as_uint(f);
  u += 0x7fff + ((u >> 16) & 1);   // RNE
  return (unsigned short)(u >> 16);
}
DEV float fexp2(float x) {
  float r;
  asm("v_exp_f32 %0, %1" : "=v"(r) : "v"(x));
  return r;
}
DEV unsigned cvtpk(float lo, float hi) {
  unsigned r;
  asm("v_cvt_pk_bf16_f32 %0, %1, %2" : "=v"(r) : "v"(lo), "v"(hi));
  return r;
}

// ---------------- cast f32 -> bf16 (vectorized) ----------------
__global__ __launch_bounds__(256) void k_cast(const float* __restrict__ in,
                                              ushort* __restrict__ out, int n4) {
  int i = blockIdx.x * 256 + threadIdx.x;
  if (i >= n4) return;
  float4 v = reinterpret_cast<const float4*>(in)[i];
  ushort4 o;
  o.x = f2bf(v.x); o.y = f2bf(v.y); o.z = f2bf(v.z); o.w = f2bf(v.w);
  reinterpret_cast<ushort4*>(out)[i] = o;
}

// ---------------- GEMM: 2-phase prefetch, global_load_lds staging ----------------
// EPI 0: C -> bf16 ; EPI 1: C+bias, fast gelu -> bf16 ; EPI 2: C+bias+resid -> f32
// QKV: Bt virtual [3*DM][K]; outputs to 3 contig buffers; K-third written with
// in-row 64-elem XOR swizzle so attn can global_load_lds it linearly (T21).
template <int EPI, int BN, bool QKV>
__global__ __launch_bounds__(256) void k_gemm(
    const ushort* __restrict__ A, const ushort* __restrict__ Bt,
    const float* __restrict__ bias, const float* __restrict__ resid,
    ushort* __restrict__ Cb, float* __restrict__ Cf,
    int K, int nbx) {
  __shared__ ushort As[2][128][32];
  __shared__ ushort Bs[2][BN][32];

  const int t = threadIdx.x;
  const int lane = t & 63, w = t >> 6;
  const int lr = lane & 15, lg = lane >> 4;
  const int lrow = lane >> 2, lc8 = (lane & 3) * 8;

  // bijective XCD chunking (m204) + group-of-4-rows decode
  const int nwg = gridDim.x;
  const int bid = blockIdx.x;
  const int q8 = nwg >> 3, r8 = nwg & 7;
  const int xcd = bid & 7, lin = bid >> 3;
  const int wg = (xcd < r8 ? xcd * (q8 + 1) : r8 * (q8 + 1) + (xcd - r8) * q8) + lin;
  const int band = wg / (4 * nbx);
  const int inn  = wg % (4 * nbx);
  const int by = band * 4 + (inn & 3);
  const int bx = inn >> 2;

  const int bRow = by * 128;
  const int bCol = bx * BN;

  constexpr int NW = BN / 32;
  const int wRow = (w >> 1) * 64, wCol = (w & 1) * (BN / 2);

  const f32x4 zero = {0.f, 0.f, 0.f, 0.f};
  f32x4 acc[4][NW];
#pragma unroll
  for (int m = 0; m < 4; ++m)
#pragma unroll
    for (int n = 0; n < NW; ++n) acc[m][n] = zero;

  auto stage = [&](int buf, int kt) {
#pragma unroll
    for (int i = 0; i < 2; ++i) {
      int rr = w * 32 + i * 16;
      __builtin_amdgcn_global_load_lds(
          AS1(A + (size_t)(bRow + rr + lrow) * K + kt + lc8),
          AS3(&As[buf][rr][0]), 16, 0, 0);
    }
#pragma unroll
    for (int i = 0; i < BN / 64; ++i) {
      int rr = w * (BN / 4) + i * 16;
      __builtin_amdgcn_global_load_lds(
          AS1(Bt + (size_t)(bCol + rr + lrow) * K + kt + lc8),
          AS3(&Bs[buf][rr][0]), 16, 0, 0);
    }
  };

  stage(0, 0);
  const int nk = K / 32;
  for (int tt = 0; tt < nk; ++tt) {
    const int cur = tt & 1;
    __syncthreads();
    if (tt + 1 < nk) stage(cur ^ 1, (tt + 1) * 32);

    s16x8 af[4], bfr[NW];
#pragma unroll
    for (int m = 0; m < 4; ++m)
      af[m] = *reinterpret_cast<const s16x8*>(&As[cur][wRow + m * 16 + lr][lg * 8]);
#pragma unroll
    for (int n = 0; n < NW; ++n)
      bfr[n] = *reinterpret_cast<const s16x8*>(&Bs[cur][wCol + n * 16 + lr][lg * 8]);
#pragma unroll
    for (int m = 0; m < 4; ++m)
#pragma unroll
      for (int n = 0; n < NW; ++n)
        acc[m][n] = __builtin_amdgcn_mfma_f32_16x16x32_bf16(af[m], bfr[n], acc[m][n], 0, 0, 0);
  }

  // ---- epilogue ----
  ushort* CbOut = Cb;
  int colBase = bCol, Ncols = nbx * BN, third = 0;
  if (QKV) {
    third = bCol >> 10;
    CbOut = Cb + (size_t)third * ROWS * DM;
    colBase = bCol & 1023;
    Ncols = DM;
  }
#pragma unroll
  for (int m = 0; m < 4; ++m) {
    int gr = bRow + wRow + m * 16 + lg * 4;
#pragma unroll
    for (int n = 0; n < NW; ++n) {
      int gc = colBase + wCol + n * 16 + lr;
      float bv = (EPI == 1 || EPI == 2) ? bias[gc] : 0.0f;
#pragma unroll
      for (int r = 0; r < 4; ++r) {
        int nr = gr + r;
        float v = acc[m][n][r] + bv;
        if (EPI == 2) {
          size_t idx = (size_t)nr * Ncols + gc;
          Cf[idx] = v + resid[idx];
        } else if (EPI == 1) {
          size_t idx = (size_t)nr * Ncols + gc;
          float u = v + 0.044715f * v * v * v;
          float g = v / (1.0f + __expf(-1.5957691216057308f * u));
          CbOut[idx] = f2bf(g);
        } else {
          int gcs = gc;
          if (QKV && third == 1)   // pre-swizzle K rows for attn's linear gload_lds
            gcs = (gc & ~63) | ((gc ^ ((nr & 7) << 3)) & 63);
          CbOut[(size_t)nr * Ncols + gcs] = f2bf(v);
        }
      }
    }
  }
}

// ---------------- V transpose: vbuf[b][n][h][d] -> vT[bh][d][n], pre-swizzled ----
__global__ __launch_bounds__(256) void k_vt(const ushort* __restrict__ V,
                                            ushort* __restrict__ vT) {
  __shared__ ushort Ls[64][72];
  const int t = threadIdx.x;
  const int n0 = blockIdx.x * 64;
  const int bh = blockIdx.y;
  const int b = bh >> 4, h = bh & 15;
  const int n = t >> 2;
#pragma unroll
  for (int half = 0; half < 2; ++half) {
    int c8 = ((t & 3) + half * 4) * 8;
    int4 v = *reinterpret_cast<const int4*>(
        V + ((size_t)(b * NN + n0 + n)) * DM + h * DK + c8);
    *reinterpret_cast<int4*>(&Ls[n][c8]) = v;
  }
  __syncthreads();
  const int d = t >> 2;
#pragma unroll
  for (int half = 0; half < 2; ++half) {
    int c = (t & 3) + half * 4;            // 8-elem chunk index 0..7
    ushort tmp[8];
#pragma unroll
    for (int j = 0; j < 8; ++j) tmp[j] = Ls[c * 8 + j][d];
    size_t out = ((size_t)bh * DK + d) * NN + n0 + ((c ^ (d & 7)) * 8);
    *reinterpret_cast<int4*>(vT + out) = *reinterpret_cast<const int4*>(tmp);
  }
}

// ---------------- LayerNorm over D=1024 rows ----------------
template <int WB>
__global__ __launch_bounds__(256) void k_ln(const float* __restrict__ in,
                                            const float* __restrict__ g,
                                            const float* __restrict__ bta,
                                            float* __restrict__ outf,
                                            ushort* __restrict__ outb) {
  const int row = blockIdx.x;
  const int t = threadIdx.x;
  float4 v = reinterpret_cast<const float4*>(in + (size_t)row * DM)[t];
  float s1 = v.x + v.y + v.z + v.w;
  float s2 = v.x * v.x + v.y * v.y + v.z * v.z + v.w * v.w;
#pragma unroll
  for (int m = 32; m; m >>= 1) {
    s1 += __shfl_xor(s1, m, 64);
    s2 += __shfl_xor(s2, m, 64);
  }
  __shared__ float red[2][4];
  if ((t & 63) == 0) { red[0][t >> 6] = s1; red[1][t >> 6] = s2; }
  __syncthreads();
  s1 = red[0][0] + red[0][1] + red[0][2] + red[0][3];
  s2 = red[1][0] + red[1][1] + red[1][2] + red[1][3];
  const float mu = s1 * (1.0f / DM);
  const float var = s2 * (1.0f / DM) - mu * mu;
  const float rstd = rsqrtf(var + 1e-5f);
  float4 gv = reinterpret_cast<const float4*>(g)[t];
  float4 bv = reinterpret_cast<const float4*>(bta)[t];
  float4 o;
  o.x = (v.x - mu) * rstd * gv.x + bv.x;
  o.y = (v.y - mu) * rstd * gv.y + bv.y;
  o.z = (v.z - mu) * rstd * gv.z + bv.z;
  o.w = (v.w - mu) * rstd * gv.w + bv.w;
  reinterpret_cast<float4*>(outf + (size_t)row * DM)[t] = o;
  if (WB) {
    ushort4 ob;
    ob.x = f2bf(o.x); ob.y = f2bf(o.y); ob.z = f2bf(o.z); ob.w = f2bf(o.w);
    reinterpret_cast<ushort4*>(outb + (size_t)row * DM)[t] = ob;
  }
}

// ---------------- causal flash attention: swapped 32x32, gload_lds, dbuf ------
// grid (N/128, B*H), 4 waves x 32q. KVBLK=64. K pre-swizzled in kbuf,
// V pre-transposed+swizzled in vT. One barrier per tile; stage(t+1) overlaps
// compute(t). exp2-domain softmax, defer-rescale, diag-only masking.
__global__ __launch_bounds__(256) void k_attn(const ushort* __restrict__ Q,
                                              const ushort* __restrict__ Kb,
                                              const ushort* __restrict__ vT,
                                              ushort* __restrict__ O) {
  __shared__ ushort Ks[2][64 * 64];
  __shared__ ushort Vs[2][64 * 64];

  const int t = threadIdx.x;
  const int qi = (NN / 128 - 1) - (int)blockIdx.x;   // heavy blocks first
  const int bh = blockIdx.y;
  const int lane = t & 63, wid = t >> 6;
  const int l31 = lane & 31, hi = lane >> 5;
  const int q0w = qi * 128 + wid * 32;
  const size_t base = (size_t)bh * NN * DM / HH * HH;  // = b*NN*DM + ... compute directly:
  const size_t qbase = ((size_t)(bh >> 4) * NN) * DM + (bh & 15) * DK;
  const size_t vbase = (size_t)bh * DK * NN;
  (void)base;

  const float C = 0.18033688011112043f;   // 0.125 * log2(e)

  // Q frags: B-operand of mfma(K,Q): lane q=l31, d = c*16 + hi*8 + j
  s16x8 qf[4];
#pragma unroll
  for (int c = 0; c < 4; ++c)
    qf[c] = *reinterpret_cast<const s16x8*>(Q + qbase + (size_t)(q0w + l31) * DM + c * 16 + hi * 8);

  float mrun = -1e30f, lrun = 0.f, negcm = 1e30f;
  f32x16 accO[2];
#pragma unroll
  for (int dt = 0; dt < 2; ++dt)
#pragma unroll
    for (int r = 0; r < 16; ++r) accO[dt][r] = 0.f;

  auto stage = [&](int buf, int kt) {
    const int kk = kt * 64;
#pragma unroll
    for (int i = 0; i < 2; ++i) {
      int row0 = wid * 16 + i * 8;
      __builtin_amdgcn_global_load_lds(
          AS1(Kb + qbase + (size_t)(kk + row0 + (lane >> 3)) * DM + (lane & 7) * 8),
          AS3(&Ks[buf][row0 * 64]), 16, 0, 0);
      __builtin_amdgcn_global_load_lds(
          AS1(vT + vbase + (size_t)(row0 + (lane >> 3)) * NN + kk + (lane & 7) * 8),
          AS3(&Vs[buf][row0 * 64]), 16, 0, 0);
    }
  };

  const int nkt = 2 * qi + 2;
  stage(0, 0);
  for (int kt = 0; kt < nkt; ++kt) {
    const int cur = kt & 1;
    const int kk = kt * 64;
    __syncthreads();                       // stage(kt) visible; buf[cur^1] free
    if (kt + 1 < nkt) stage(cur ^ 1, kt + 1);

    if (kk <= q0w + 31) {
      const char* KsB = (const char*)Ks[cur];
      const char* VsB = (const char*)Vs[cur];
      const bool diag = (kk + 64 > q0w);
      const int nsub = (kk + 32 <= q0w + 31) ? 2 : 1;   // wave-uniform

      // ---- S^T = K Q^T ----
      f32x16 st[2];
#pragma unroll
      for (int sub = 0; sub < 2; ++sub) {
        if (sub >= nsub) break;
#pragma unroll
        for (int r = 0; r < 16; ++r) st[sub][r] = 0.f;
        const int row = sub * 32 + l31;
        const int swz = (row & 7) << 4;
#pragma unroll
        for (int c = 0; c < 4; ++c) {
          s16x8 kf = *reinterpret_cast<const s16x8*>(KsB + row * 128 + ((c * 32 + hi * 16) ^ swz));
          st[sub] = __builtin_amdgcn_mfma_f32_32x32x16_bf16(kf, qf[c], st[sub], 0, 0, 0);
        }
      }

      // ---- raw scores + mask (diag only) + max ----
      const int q = q0w + l31;
      float p[32];
#pragma unroll
      for (int sub = 0; sub < 2; ++sub) {
        if (sub >= nsub) break;
#pragma unroll
        for (int r = 0; r < 16; ++r) {
          float v = st[sub][r];
          if (diag) {
            int kl = sub * 32 + (r & 3) + 8 * (r >> 2) + 4 * hi;
            if (kk + kl > q) v = -1e30f;
          }
          p[sub * 16 + r] = v;
        }
      }
      float a[16];
#pragma unroll
      for (int i = 0; i < 16; ++i) a[i] = (nsub == 2) ? fmaxf(p[i], p[i + 16]) : p[i];
#pragma unroll
      for (int s = 8; s; s >>= 1)
#pragma unroll
        for (int i = 0; i < 8; ++i) if (i < s) a[i] = fmaxf(a[i], a[i + s]);
      float rm = fmaxf(a[0], __shfl_xor(a[0], 32, 64));

      // ---- defer-rescale: only when max grows ----
      if (__any(rm > mrun)) {
        const float mn = fmaxf(mrun, rm);
        const float alpha = fexp2(C * (mrun - mn));
        mrun = mn;
        negcm = -C * mn;
        lrun *= alpha;
#pragma unroll
        for (int dt = 0; dt < 2; ++dt) accO[dt] *= alpha;
      }

      // ---- p = exp2(C*s - C*m), sum ----
#pragma unroll
      for (int sub = 0; sub < 2; ++sub) {
        if (sub >= nsub) break;
#pragma unroll
        for (int i = 0; i < 16; ++i)
          p[sub * 16 + i] = fexp2(fmaf(p[sub * 16 + i], C, negcm));
      }
#pragma unroll
      for (int i = 0; i < 16; ++i) a[i] = (nsub == 2) ? (p[i] + p[i + 16]) : p[i];
#pragma unroll
      for (int s = 8; s; s >>= 1)
#pragma unroll
        for (int i = 0; i < 8; ++i) if (i < s) a[i] += a[i + s];
      lrun += a[0] + __shfl_xor(a[0], 32, 64);

      // ---- pack P^T frags (cvt_pk + permlane32_swap) ----
      s16x8 pf[4];
#pragma unroll
      for (int sub = 0; sub < 2; ++sub) {
        if (sub >= nsub) break;
#pragma unroll
        for (int half = 0; half < 2; ++half) {
          const float* pp = &p[sub * 16 + half * 8];
          unsigned X0 = cvtpk(pp[0], pp[1]);
          unsigned X1 = cvtpk(pp[2], pp[3]);
          unsigned Y0 = cvtpk(pp[4], pp[5]);
          unsigned Y1 = cvtpk(pp[6], pp[7]);
          asm volatile("v_permlane32_swap_b32 %0, %1" : "+v"(X0), "+v"(Y0));
          asm volatile("v_permlane32_swap_b32 %0, %1" : "+v"(X1), "+v"(Y1));
          union { unsigned u[4]; s16x8 v; } uu;
          uu.u[0] = X0; uu.u[1] = X1; uu.u[2] = Y0; uu.u[3] = Y1;
          pf[sub * 2 + half] = uu.v;
        }
      }

      // ---- O^T += V^T P^T (skip dead upper half on even-diag) ----
#pragma unroll
      for (int dt = 0; dt < 2; ++dt) {
        const int d = dt * 32 + l31;
        const int vswz = (d & 7) << 4;
#pragma unroll
        for (int kc = 0; kc < 4; ++kc) {
          if (kc >= nsub * 2) break;
          s16x8 vf = *reinterpret_cast<const s16x8*>(VsB + d * 128 + ((kc * 32 + hi * 16) ^ vswz));
          accO[dt] = __builtin_amdgcn_mfma_f32_32x32x16_bf16(vf, pf[kc], accO[dt], 0, 0, 0);
        }
      }
    }
  }

  // ---- epilogue ----
  const int q = q0w + l31;
  const float inv = 1.0f / lrun;
#pragma unroll
  for (int dt = 0; dt < 2; ++dt)
#pragma unroll
    for (int rg = 0; rg < 4; ++rg) {
      int d0 = 8 * rg + 4 * hi + 32 * dt;
      ushort4 ov;
      ov.x = f2bf(accO[dt][rg * 4 + 0] * inv);
      ov.y = f2bf(accO[dt][rg * 4 + 1] * inv);
      ov.z = f2bf(accO[dt][rg * 4 + 2] * inv);
      ov.w = f2bf(accO[dt][rg * 4 + 3] * inv);
      *reinterpret_cast<ushort4*>(O + qbase + (size_t)q * DM + d0) = ov;
    }
}

// ---------------- launch ----------------
extern "C" void kernel_launch(void* const* d_in, const int* in_sizes, int n_in,
                              void* d_out, int out_size, void* d_ws, size_t ws_size,
                              hipStream_t stream) {
  const float* tgt = (const float*)d_in[0];
  const float* Wq  = (const float*)d_in[3];
  const float* Wk  = (const float*)d_in[4];
  const float* Wv  = (const float*)d_in[5];
  const float* Wo  = (const float*)d_in[6];
  const float* bo  = (const float*)d_in[7];
  const float* W1  = (const float*)d_in[8];
  const float* b1  = (const float*)d_in[9];
  const float* W2  = (const float*)d_in[10];
  const float* b2  = (const float*)d_in[11];
  const float* g1  = (const float*)d_in[12];
  const float* be1 = (const float*)d_in[13];
  const float* g2  = (const float*)d_in[14];
  const float* be2 = (const float*)d_in[15];

  char* ws = (char*)d_ws;
  size_t off = 0;
  auto alloc = [&](size_t bytes) {
    void* p = ws + off;
    off += (bytes + 255) & ~(size_t)255;
    return p;
  };
  ushort* xb   = (ushort*)alloc((size_t)ROWS * DM * 2);
  ushort* wqb  = (ushort*)alloc((size_t)DM * DM * 2);   // wq|wk|wv contiguous
  ushort* wkb  = (ushort*)alloc((size_t)DM * DM * 2);
  ushort* wvb  = (ushort*)alloc((size_t)DM * DM * 2);
  ushort* wob  = (ushort*)alloc((size_t)DM * DM * 2);
  ushort* w1b  = (ushort*)alloc((size_t)FF * DM * 2);
  ushort* w2b  = (ushort*)alloc((size_t)DM * FF * 2);
  ushort* qbuf = (ushort*)alloc((size_t)ROWS * DM * 2); // q|k|v contiguous
  ushort* kbuf = (ushort*)alloc((size_t)ROWS * DM * 2);
  ushort* vbuf = (ushort*)alloc((size_t)ROWS * DM * 2);
  ushort* vtb  = (ushort*)alloc((size_t)ROWS * DM * 2); // V^T [bh][d][n], swizzled
  ushort* atnb = (ushort*)alloc((size_t)ROWS * DM * 2);
  float*  h1   = (float*)alloc((size_t)ROWS * DM * 4);  // reused as z
  float*  x1f  = (float*)alloc((size_t)ROWS * DM * 4);
  ushort* x1b  = (ushort*)alloc((size_t)ROWS * DM * 2);
  ushort* t1b  = (ushort*)alloc((size_t)ROWS * FF * 2);
  (void)ws_size; (void)in_sizes; (void)n_in; (void)out_size;
  (void)wkb; (void)wvb; (void)kbuf;

  auto cast = [&](const float* src, ushort* dst, size_t n) {
    int n4 = (int)(n / 4);
    k_cast<<<dim3((n4 + 255) / 256), 256, 0, stream>>>(src, dst, n4);
  };
  cast(tgt, xb, (size_t)ROWS * DM);
  cast(Wq, wqb, (size_t)DM * DM);
  cast(Wk, wkb, (size_t)DM * DM);
  cast(Wv, wvb, (size_t)DM * DM);
  cast(Wo, wob, (size_t)DM * DM);
  cast(W1, w1b, (size_t)FF * DM);
  cast(W2, w2b, (size_t)DM * FF);

  dim3 blk(256);
  // fused QKV (K-third pre-swizzled in epilogue)
  k_gemm<0, 128, true><<<dim3(24 * 32), blk, 0, stream>>>(
      xb, wqb, nullptr, nullptr, qbuf, nullptr, DM, 24);

  k_vt<<<dim3(NN / 64, Bb * HH), blk, 0, stream>>>(vbuf, vtb);

  k_attn<<<dim3(NN / 128, Bb * HH), blk, 0, stream>>>(qbuf, kbuf, vtb, atnb);

  // O-projection + bo + residual(tgt) -> f32 h1
  k_gemm<2, 64, false><<<dim3(16 * 32), blk, 0, stream>>>(
      atnb, wob, bo, tgt, nullptr, h1, DM, 16);
  k_ln<1><<<dim3(ROWS), blk, 0, stream>>>(h1, g1, be1, x1f, x1b);

  // FFN
  k_gemm<1, 128, false><<<dim3(32 * 32), blk, 0, stream>>>(
      x1b, w1b, b1, nullptr, t1b, nullptr, DM, 32);
  float* z = h1;
  k_gemm<2, 64, false><<<dim3(16 * 32), blk, 0, stream>>>(
      t1b, w2b, b2, x1f, nullptr, z, FF, 16);
  k_ln<0><<<dim3(ROWS), blk, 0, stream>>>(z, g2, be2, (float*)d_out, nullptr);
}